// Round 1
// 1107.385 us; speedup vs baseline: 1.1848x; 1.1848x over previous
//
#include <hip/hip_runtime.h>
#include <hip/hip_bf16.h>

// MambaSSMBlock: HID=1024, STATE=16, K=4, EXPAND=2, INNER=2048, B=4, L=4096
#define HID   1024
#define STATE 16
#define KCONV 4
#define INNER 2048
#define BSZ   4
#define LSEQ  4096
#define BL    (BSZ * LSEQ)       // 16384 rows
#define NCAT  2176               // 2048 (dt) + 16 (B) + 16 (C) + 96 pad -> 17 tiles of 128
#define NCH   64                 // scan chunks
#define TC    64                 // steps per chunk (NCH*TC == LSEQ)

typedef unsigned short ushort_t;
typedef unsigned int   uint_t;
typedef __attribute__((ext_vector_type(8))) __bf16 bf16x8;
typedef __attribute__((ext_vector_type(4))) float  f32x4;
typedef __attribute__((ext_vector_type(8))) unsigned short u16x8;

// ---------- helpers ----------
__device__ __forceinline__ ushort_t f2bf(float f) {
    uint_t u = __float_as_uint(f);
    u += 0x7fffu + ((u >> 16) & 1u);       // RNE (finite values only here)
    return (ushort_t)(u >> 16);
}
__device__ __forceinline__ float bf2f(ushort_t h) {
    return __uint_as_float(((uint_t)h) << 16);
}

#define AS1 __attribute__((address_space(1)))
#define AS3 __attribute__((address_space(3)))
__device__ __forceinline__ void async_copy16(const ushort_t* g, ushort_t* l) {
    // LDS dest is wave-uniform base; HW writes lane i at base + i*16B
    __builtin_amdgcn_global_load_lds((const AS1 void*)g, (AS3 void*)l, 16, 0, 0);
}

// ---------- elementwise cast ----------
__global__ void cast_bf16_kernel(const float* __restrict__ src, ushort_t* __restrict__ dst, int n) {
    int i = blockIdx.x * 256 + threadIdx.x;
    if (i < n) dst[i] = f2bf(src[i]);
}

// ---------- build concatenated [dt_w; B_w; C_w; 0-pad] bf16 weight (NCAT x 2048) ----------
__global__ void build_wcat_kernel(const float* __restrict__ dtw, const float* __restrict__ Bw,
                                  const float* __restrict__ Cw, ushort_t* __restrict__ out) {
    int i = blockIdx.x * 256 + threadIdx.x;
    if (i >= NCAT * INNER) return;
    int r = i >> 11;           // / 2048
    int k = i & (INNER - 1);
    float v = 0.f;
    if (r < INNER)            v = dtw[i];
    else if (r < INNER + 16)  v = Bw[(r - INNER) * INNER + k];
    else if (r < INNER + 32)  v = Cw[(r - INNER - 16) * INNER + k];
    out[i] = f2bf(v);
}

__global__ void build_biascat_kernel(const float* __restrict__ dtb, const float* __restrict__ Bb,
                                     const float* __restrict__ Cb, float* __restrict__ out) {
    int i = blockIdx.x * 256 + threadIdx.x;
    if (i >= NCAT) return;
    float v = 0.f;
    if (i < INNER)            v = dtb[i];
    else if (i < INNER + 16)  v = Bb[i - INNER];
    else if (i < INNER + 32)  v = Cb[i - INNER - 16];
    out[i] = v;
}

// ---------- bf16 MFMA GEMM: C = A(M,K) @ B(N,K)^T, 128x128x32 tiles ----------
// MODE 0: in_proj  -> col<2048: x_part bf16 (oU0); col>=2048: silu(z) bf16 (oU1)
// MODE 1: dt/Bm/Cm -> col<2048: softplus -> dt bf16 (oU0); [2048,2064): Bm fp32; [2064,2080): Cm fp32
// MODE 2: out_proj -> plain bias add, fp32 to oF
//
// XCD-banded swizzle (T1): dispatch id lb -> xcd = lb%8, slot = lb/8. Each XCD
// owns a contiguous band of gridY/8 = 16 row-tiles, x-fastest within the band.
//
// K-loop: T3-minimal 2-phase double buffer. Stage tile t+1 into buf^1 BEFORE
// computing tile t from buf[cur]; single __syncthreads() per iteration at the
// END (its vmcnt(0) drain lands after ~200cy of ds_read+MFMA have covered the
// global->LDS latency). Previous version staged into a single buffer and
// drained immediately -> zero latency overlap (m233: 2ph stall = 72%).
#define BM 128
#define BN 128
#define BK 32

template <int MODE>
__global__ __launch_bounds__(256) void gemm_bt_kernel(
    const ushort_t* __restrict__ A, const ushort_t* __restrict__ Bw,
    const float* __restrict__ bias,
    ushort_t* __restrict__ oU0, ushort_t* __restrict__ oU1,
    float* __restrict__ oF, float* __restrict__ oB, float* __restrict__ oC,
    int N, int K)
{
    __shared__ ushort_t As[2][BM * BK];
    __shared__ ushort_t Bs[2][BN * BK];

    const int tid  = threadIdx.x;
    const int w    = tid >> 6;
    const int lane = tid & 63;

    // ----- XCD-banded swizzle (gridDim.y == 128 for all launches here) -----
    const int nx   = gridDim.x;
    const int lb   = blockIdx.y * nx + blockIdx.x;   // dispatch linear id (x-fastest)
    const int xcd  = lb & 7;
    const int slot = lb >> 3;
    const int tx   = slot % nx;
    const int ty   = xcd * 16 + slot / nx;           // 16 row-tiles per XCD band
    const int row0 = ty * BM;
    const int col0 = tx * BN;

    const int m16 = lane & 15;
    const int ko8 = lane >> 4;

    // staging: wave w fills rows [w*32, w*32+32); lane i -> row i/4, cols (i&3)*8..+8
    const int srow  = w * 32 + (lane >> 2);
    const int scol8 = (lane & 3) * 8;

    f32x4 acc[4][4] = {};

    const int wr = (w >> 1) * 64;
    const int wc = (w & 1) * 64;

    const ushort_t* ga = A  + (size_t)(row0 + srow) * K + scol8;
    const ushort_t* gb = Bw + (size_t)(col0 + srow) * K + scol8;

#define STAGE(buf, kk)                                                        \
    do {                                                                      \
        async_copy16(ga + (kk),                  &As[buf][(w * 32) * BK]);    \
        async_copy16(ga + (kk) + (size_t)16 * K, &As[buf][(w * 32 + 16) * BK]);\
        async_copy16(gb + (kk),                  &Bs[buf][(w * 32) * BK]);    \
        async_copy16(gb + (kk) + (size_t)16 * K, &Bs[buf][(w * 32 + 16) * BK]);\
    } while (0)

    // prologue: stage tile 0; __syncthreads drains vmcnt(0) -> buf0 ready
    STAGE(0, 0);
    __syncthreads();

    int cur = 0;
    for (int k0 = 0; k0 < K; k0 += BK) {
        if (k0 + BK < K) STAGE(cur ^ 1, k0 + BK);    // prefetch next tile (in flight across compute)

        bf16x8 af[4], bfr[4];
#pragma unroll
        for (int i = 0; i < 4; i++)
            af[i] = *(const bf16x8*)&As[cur][(wr + i * 16 + m16) * BK + ko8 * 8];
#pragma unroll
        for (int j = 0; j < 4; j++)
            bfr[j] = *(const bf16x8*)&Bs[cur][(wc + j * 16 + m16) * BK + ko8 * 8];
#pragma unroll
        for (int i = 0; i < 4; i++)
#pragma unroll
            for (int j = 0; j < 4; j++)
                acc[i][j] = __builtin_amdgcn_mfma_f32_16x16x32_bf16(af[i], bfr[j], acc[i][j], 0, 0, 0);

        __syncthreads();   // one barrier/iter: drains prefetch vmcnt + read-done fence
        cur ^= 1;
    }
#undef STAGE

    // epilogue: C/D layout col = lane&15, row = (lane>>4)*4 + reg
    const int rbase = (lane >> 4) * 4;
#pragma unroll
    for (int i = 0; i < 4; i++) {
#pragma unroll
        for (int j = 0; j < 4; j++) {
#pragma unroll
            for (int r = 0; r < 4; r++) {
                int row = row0 + wr + i * 16 + rbase + r;
                int col = col0 + wc + j * 16 + m16;
                float v = acc[i][j][r] + bias[col];
                if (MODE == 0) {
                    if (col < INNER) {
                        oU0[(size_t)row * INNER + col] = f2bf(v);                // x_part bf16
                    } else {
                        float s = v / (1.f + __expf(-v));                        // silu(z)
                        oU1[(size_t)row * INNER + (col - INNER)] = f2bf(s);
                    }
                } else if (MODE == 1) {
                    if (col < INNER) {
                        float sp = fmaxf(v, 0.f) + log1pf(__expf(-fabsf(v)));    // softplus
                        oU0[(size_t)row * INNER + col] = f2bf(sp);               // dt bf16
                    } else if (col < INNER + 16) {
                        oB[(size_t)row * STATE + (col - INNER)] = v;             // Bm fp32
                    } else if (col < INNER + 32) {
                        oC[(size_t)row * STATE + (col - INNER - 16)] = v;        // Cm fp32
                    } // pad cols dropped
                } else {
                    oF[(size_t)row * N + col] = v;                               // d_out fp32
                }
            }
        }
    }
}

// ---------- causal depthwise conv (K=4) + silu; bf16 in, bf16 out ----------
__global__ void conv_silu_kernel(const ushort_t* __restrict__ xp, const float* __restrict__ cw,
                                 const float* __restrict__ cb,
                                 ushort_t* __restrict__ xcbf) {
    int i = blockIdx.x * 256 + threadIdx.x;     // over BL*INNER
    int d  = i & (INNER - 1);
    int bl = i >> 11;
    int l  = bl & (LSEQ - 1);
    float acc = cb[d];
#pragma unroll
    for (int k = 0; k < KCONV; k++) {
        int ls = l - (KCONV - 1) + k;
        if (ls >= 0) acc = fmaf(cw[d * KCONV + k], bf2f(xp[i + (ls - l) * INNER]), acc);
    }
    float s = acc / (1.f + __expf(-acc));
    xcbf[i] = f2bf(s);
}

// ---------- chunked parallel scan, thread-per-channel ----------
__global__ __launch_bounds__(256) void scan_pass1(
    const ushort_t* __restrict__ dt, const ushort_t* __restrict__ xc,
    const float* __restrict__ Bm, const float* __restrict__ A_log,
    ushort_t* __restrict__ Pc, float* __restrict__ Sc)
{
    const int b = blockIdx.z;
    const int c = blockIdx.y;
    const int d = blockIdx.x * 256 + threadIdx.x;

    float A[STATE], h[STATE];
    {
        float al[STATE];
#pragma unroll
        for (int q = 0; q < 4; q++)
            *(f32x4*)(al + q * 4) = *(const f32x4*)(A_log + (size_t)d * STATE + q * 4);
#pragma unroll
        for (int s = 0; s < STATE; s++) { A[s] = -__expf(al[s]); h[s] = 0.f; }
    }
    float sdt = 0.f;
    const size_t base = (size_t)b * LSEQ + (size_t)c * TC;

#pragma unroll 2
    for (int t = 0; t < TC; t++) {
        const size_t r = base + t;
        const float dtv = bf2f(dt[r * INNER + d]);
        const float xv  = bf2f(xc[r * INNER + d]);
        const float dtx = dtv * xv;
        float Bv[STATE];
#pragma unroll
        for (int q = 0; q < 4; q++)
            *(f32x4*)(Bv + q * 4) = *(const f32x4*)(Bm + r * STATE + q * 4);
        sdt += dtv;
#pragma unroll
        for (int s = 0; s < STATE; s++) {
            const float dA = __expf(dtv * A[s]);
            h[s] = fmaf(dA, h[s], dtx * Bv[s]);
        }
    }

    const size_t idx = ((size_t)(b * NCH + c) * INNER + d) * STATE;
#pragma unroll
    for (int q = 0; q < 4; q++)
        *(f32x4*)(Sc + idx + q * 4) = *(const f32x4*)(h + q * 4);
    u16x8 p0, p1;
#pragma unroll
    for (int s = 0; s < 8; s++) { p0[s] = f2bf(__expf(A[s] * sdt)); }
#pragma unroll
    for (int s = 0; s < 8; s++) { p1[s] = f2bf(__expf(A[s + 8] * sdt)); }
    *(u16x8*)(Pc + idx)     = p0;
    *(u16x8*)(Pc + idx + 8) = p1;
}

// Pass 2: exclusive scan over chunks (in-place: S becomes H = chunk-initial state).
__global__ __launch_bounds__(256) void scan_pass2(
    const ushort_t* __restrict__ Pc, float* Sc)
{
    const int i = blockIdx.x * 256 + threadIdx.x;      // over BSZ*INNER*STATE
    const int b   = i >> 15;                           // / (INNER*STATE)
    const int rem = i & (INNER * STATE - 1);
    float H = 0.f;
#pragma unroll 8
    for (int c = 0; c < NCH; c++) {
        const size_t idx = (size_t)(b * NCH + c) * (INNER * STATE) + rem;
        const float Pv = bf2f(Pc[idx]);
        const float Sv = Sc[idx];
        const float Hn = fmaf(Pv, H, Sv);
        Sc[idx] = H;                                   // exclusive: h at chunk start
        H = Hn;
    }
}

// Pass 3: re-run local scan seeded with H; y = sum_s h[s]*C[s] + D*x; gate with
// silu(z) in-place. No shuffles: states are registers.
__global__ __launch_bounds__(256) void scan_pass3(
    const ushort_t* __restrict__ dt, const ushort_t* __restrict__ xc,
    const float* __restrict__ Bm, const float* __restrict__ Cm,
    const float* __restrict__ A_log, const float* __restrict__ Dv,
    const float* __restrict__ Hc, ushort_t* sz_y)
{
    const int b = blockIdx.z;
    const int c = blockIdx.y;
    const int d = blockIdx.x * 256 + threadIdx.x;

    float A[STATE], h[STATE];
    {
        float al[STATE];
#pragma unroll
        for (int q = 0; q < 4; q++)
            *(f32x4*)(al + q * 4) = *(const f32x4*)(A_log + (size_t)d * STATE + q * 4);
#pragma unroll
        for (int s = 0; s < STATE; s++) A[s] = -__expf(al[s]);
    }
    const size_t hidx = ((size_t)(b * NCH + c) * INNER + d) * STATE;
#pragma unroll
    for (int q = 0; q < 4; q++)
        *(f32x4*)(h + q * 4) = *(const f32x4*)(Hc + hidx + q * 4);

    const float Dd = Dv[d];
    const size_t base = (size_t)b * LSEQ + (size_t)c * TC;

#pragma unroll 2
    for (int t = 0; t < TC; t++) {
        const size_t r = base + t;
        const float dtv = bf2f(dt[r * INNER + d]);
        const float xv  = bf2f(xc[r * INNER + d]);
        const float dtx = dtv * xv;
        float Bv[STATE], Cv[STATE];
#pragma unroll
        for (int q = 0; q < 4; q++) {
            *(f32x4*)(Bv + q * 4) = *(const f32x4*)(Bm + r * STATE + q * 4);
            *(f32x4*)(Cv + q * 4) = *(const f32x4*)(Cm + r * STATE + q * 4);
        }
        float y = Dd * xv;
#pragma unroll
        for (int s = 0; s < STATE; s++) {
            const float dA = __expf(dtv * A[s]);
            h[s] = fmaf(dA, h[s], dtx * Bv[s]);
            y = fmaf(h[s], Cv[s], y);
        }
        const float zv = bf2f(sz_y[r * INNER + d]);
        sz_y[r * INNER + d] = f2bf(y * zv);
    }
}

// ---------- launch ----------
extern "C" void kernel_launch(void* const* d_in, const int* in_sizes, int n_in,
                              void* d_out, int out_size, void* d_ws, size_t ws_size,
                              hipStream_t stream) {
    const float* x       = (const float*)d_in[0];
    const float* in_w    = (const float*)d_in[1];
    const float* in_b    = (const float*)d_in[2];
    const float* conv_w  = (const float*)d_in[3];
    const float* conv_b  = (const float*)d_in[4];
    const float* dt_w    = (const float*)d_in[5];
    const float* dt_b    = (const float*)d_in[6];
    const float* A_log   = (const float*)d_in[7];
    const float* B_w     = (const float*)d_in[8];
    const float* B_b     = (const float*)d_in[9];
    const float* C_w     = (const float*)d_in[10];
    const float* C_b     = (const float*)d_in[11];
    const float* Dv      = (const float*)d_in[12];
    const float* out_w   = (const float*)d_in[13];
    const float* out_b   = (const float*)d_in[14];
    float* out = (float*)d_out;

    char* ws = (char*)d_ws;
    size_t off = 0;
    auto alloc = [&](size_t bytes) { size_t o = off; off += (bytes + 255) & ~(size_t)255; return o; };

    ushort_t* Xbf     = (ushort_t*)(ws + alloc((size_t)BL * HID * 2));       // 32 MB   [dead after GEMM1]
    ushort_t* W1bf    = (ushort_t*)(ws + alloc((size_t)2 * INNER * HID * 2));// 8 MB    [dead after GEMM1]
    ushort_t* Wcat    = (ushort_t*)(ws + alloc((size_t)NCAT * INNER * 2));   // 8.5 MB  [dead after GEMM2]
    ushort_t* Woutbf  = (ushort_t*)(ws + alloc((size_t)HID * INNER * 2));    // 4 MB
    float*    biascat = (float*)   (ws + alloc((size_t)NCAT * 4));
    ushort_t* xpart   = (ushort_t*)(ws + alloc((size_t)BL * INNER * 2));     // 64 MB, reused as dt
    ushort_t* szbf    = (ushort_t*)(ws + alloc((size_t)BL * INNER * 2));     // 64 MB, y in-place
    ushort_t* xconvbf = (ushort_t*)(ws + alloc((size_t)BL * INNER * 2));     // 64 MB
    float*    Bmbuf   = (float*)   (ws + alloc((size_t)BL * STATE * 4));     // 1 MB
    float*    Cmbuf   = (float*)   (ws + alloc((size_t)BL * STATE * 4));     // 1 MB
    ushort_t* dtbuf   = xpart;   // x_part dead after conv

    // Chunk-scan scratch overlays the dead Xbf/W1bf/Wcat region (~48.5 MB):
    //   P bf16: 16 MB at ws+0; S fp32: 32 MB after (48 MB total, fits)
    ushort_t* Pbuf = (ushort_t*)ws;
    float*    Sbuf = (float*)(ws + (size_t)NCH * BSZ * INNER * STATE * 2);
    (void)in_sizes; (void)n_in; (void)out_size;

    // If workspace is too small, skip launches: harness reports clean absmax
    // failure (== max|ref|) instead of a device page-fault core dump.
    if (ws_size < off) return;

    // casts / weight packing
    {
        int n = BL * HID;
        cast_bf16_kernel<<<(n + 255) / 256, 256, 0, stream>>>(x, Xbf, n);
        n = 2 * INNER * HID;
        cast_bf16_kernel<<<(n + 255) / 256, 256, 0, stream>>>(in_w, W1bf, n);
        n = HID * INNER;
        cast_bf16_kernel<<<(n + 255) / 256, 256, 0, stream>>>(out_w, Woutbf, n);
        n = NCAT * INNER;
        build_wcat_kernel<<<(n + 255) / 256, 256, 0, stream>>>(dt_w, B_w, C_w, Wcat);
        build_biascat_kernel<<<(NCAT + 255) / 256, 256, 0, stream>>>(dt_b, B_b, C_b, biascat);
    }

    // GEMM1: xz = x @ in_proj_w^T + b  -> x_part bf16, silu(z) bf16
    gemm_bt_kernel<0><<<dim3((2 * INNER) / BN, BL / BM), 256, 0, stream>>>(
        Xbf, W1bf, in_b, xpart, szbf, nullptr, nullptr, nullptr, 2 * INNER, HID);

    // causal depthwise conv + silu -> x_conv bf16
    conv_silu_kernel<<<(BL * INNER) / 256, 256, 0, stream>>>(xpart, conv_w, conv_b, xconvbf);

    // GEMM2: [dt_pre | Bm | Cm] = x_conv @ Wcat^T + biascat ; softplus fused for dt
    gemm_bt_kernel<1><<<dim3(NCAT / BN, BL / BM), 256, 0, stream>>>(
        xconvbf, Wcat, biascat, dtbuf, nullptr, nullptr, Bmbuf, Cmbuf, NCAT, INNER);

    // chunked selective scan (+ D*x, * silu(z)) -> y_gated bf16 (in-place over silu(z))
    scan_pass1<<<dim3(INNER / 256, NCH, BSZ), 256, 0, stream>>>(
        dtbuf, xconvbf, Bmbuf, A_log, Pbuf, Sbuf);
    scan_pass2<<<(BSZ * INNER * STATE) / 256, 256, 0, stream>>>(Pbuf, Sbuf);
    scan_pass3<<<dim3(INNER / 256, NCH, BSZ), 256, 0, stream>>>(
        dtbuf, xconvbf, Bmbuf, Cmbuf, A_log, Dv, Sbuf, szbf);

    // GEMM3: out = y_gated @ out_w^T + out_b
    gemm_bt_kernel<2><<<dim3(HID / BN, BL / BM), 256, 0, stream>>>(
        szbf, Woutbf, out_b, nullptr, nullptr, out, nullptr, nullptr, HID, INNER);
}

// Round 3
// 1089.709 us; speedup vs baseline: 1.2040x; 1.0162x over previous
//
#include <hip/hip_runtime.h>
#include <hip/hip_bf16.h>

// MambaSSMBlock: HID=1024, STATE=16, K=4, EXPAND=2, INNER=2048, B=4, L=4096
#define HID   1024
#define STATE 16
#define KCONV 4
#define INNER 2048
#define BSZ   4
#define LSEQ  4096
#define BL    (BSZ * LSEQ)       // 16384 rows
#define NCAT  2304               // 2048 (dt) + 16 (B) + 16 (C) + 224 pad -> 9 tiles of 256
#define NCH   64                 // scan chunks
#define TC    64                 // steps per chunk (NCH*TC == LSEQ)

typedef unsigned short ushort_t;
typedef unsigned int   uint_t;
typedef __attribute__((ext_vector_type(8))) __bf16 bf16x8;
typedef __attribute__((ext_vector_type(4))) float  f32x4;
typedef __attribute__((ext_vector_type(8))) unsigned short u16x8;

// ---------- helpers ----------
__device__ __forceinline__ ushort_t f2bf(float f) {
    uint_t u = __float_as_uint(f);
    u += 0x7fffu + ((u >> 16) & 1u);       // RNE (finite values only here)
    return (ushort_t)(u >> 16);
}
__device__ __forceinline__ float bf2f(ushort_t h) {
    return __uint_as_float(((uint_t)h) << 16);
}

#define AS1 __attribute__((address_space(1)))
#define AS3 __attribute__((address_space(3)))
__device__ __forceinline__ void async_copy16(const ushort_t* g, ushort_t* l) {
    // LDS dest is wave-uniform base; HW writes lane i at base + i*16B
    __builtin_amdgcn_global_load_lds((const AS1 void*)g, (AS3 void*)l, 16, 0, 0);
}

// ---------- elementwise cast ----------
__global__ void cast_bf16_kernel(const float* __restrict__ src, ushort_t* __restrict__ dst, int n) {
    int i = blockIdx.x * 256 + threadIdx.x;
    if (i < n) dst[i] = f2bf(src[i]);
}

// ---------- build concatenated [dt_w; B_w; C_w; 0-pad] bf16 weight (NCAT x 2048) ----------
__global__ void build_wcat_kernel(const float* __restrict__ dtw, const float* __restrict__ Bw,
                                  const float* __restrict__ Cw, ushort_t* __restrict__ out) {
    int i = blockIdx.x * 256 + threadIdx.x;
    if (i >= NCAT * INNER) return;
    int r = i >> 11;           // / 2048
    int k = i & (INNER - 1);
    float v = 0.f;
    if (r < INNER)            v = dtw[i];
    else if (r < INNER + 16)  v = Bw[(r - INNER) * INNER + k];
    else if (r < INNER + 32)  v = Cw[(r - INNER - 16) * INNER + k];
    out[i] = f2bf(v);
}

__global__ void build_biascat_kernel(const float* __restrict__ dtb, const float* __restrict__ Bb,
                                     const float* __restrict__ Cb, float* __restrict__ out) {
    int i = blockIdx.x * 256 + threadIdx.x;
    if (i >= NCAT) return;
    float v = 0.f;
    if (i < INNER)            v = dtb[i];
    else if (i < INNER + 16)  v = Bb[i - INNER];
    else if (i < INNER + 32)  v = Cb[i - INNER - 16];
    out[i] = v;
}

// ---------- 256x256x64 8-phase bf16 MFMA GEMM: C = A(M,K) @ B(N,K)^T ----------
// 8 waves (2Mx4N), 512 threads, 128KiB LDS = 2 K-tile bufs x [B0|B1|A0|A1] x 16KB.
// Per K-tile: 4 phases, each = {ds_reads || stage 1 half-tile -> s_barrier ->
// setprio(1) 16 MFMA setprio(0) -> s_barrier}; counted vmcnt(4) once per K-tile
// (2 half-tiles in flight), vmcnt(0) only before the last tile (T3+T4).
// LDS XOR-swizzle (T2): 16B-chunk col16 ^= (row&7) within each 128B row; the
// inverse permutation is applied to the GLOBAL source address (global_load_lds
// writes linearly), the forward one on ds_read -> conflict-free ds_read_b128.
// Stage ring invariant (verified): before tile t begins, each wave's 4 newest
// loads (tile t+1 B0/B1) are the only outstanding ones; all of tile t's halves
// drained by the boundary vmcnt(4)+barrier. B-slot overwrites (q2/q3, tile t+2)
// land >=2 barriers after that slot's last ds_read.
// MODE 0: in_proj  -> col<2048: x_part bf16; col>=2048: silu(z) bf16
// MODE 1: dt/Bm/Cm -> col<2048: softplus->dt bf16; [2048,2064): Bm; [2064,2080): Cm; pad dropped
// MODE 2: out_proj -> bias add, fp32
#define mfma_bf16 __builtin_amdgcn_mfma_f32_16x16x32_bf16

template <int MODE>
__global__ __launch_bounds__(512, 2) void gemm256_kernel(
    const ushort_t* __restrict__ A, const ushort_t* __restrict__ Bw,
    const float* __restrict__ bias,
    ushort_t* __restrict__ oU0, ushort_t* __restrict__ oU1,
    float* __restrict__ oF, float* __restrict__ oB, float* __restrict__ oC,
    int N, int K)
{
    __shared__ ushort_t smem[65536];   // 128 KiB

    const int tid  = threadIdx.x;
    const int w    = tid >> 6;
    const int lane = tid & 63;
    const int m16  = lane & 15;
    const int ko   = lane >> 4;        // 0..3 : which 8-elem k-chunk
    const int wm   = w >> 2;           // 0..1 : row-half of the 256-row tile
    const int wn   = w & 3;            // 0..3 : 64-col quarter
    const int wnh  = wn >> 1;          // B half-tile index

    // ----- XCD-banded swizzle (gridDim.y == 64, nwg % 8 == 0 for all shapes) -----
    const int gx   = gridDim.x;
    const int lb   = blockIdx.y * gx + blockIdx.x;
    const int xcd  = lb & 7;
    const int slot = lb >> 3;
    const int tx   = slot % gx;
    const int ty   = xcd * 8 + slot / gx;    // 8 row-tiles per XCD band
    const int row0 = ty * 256;
    const int col0 = tx * 256;

    const int nkt  = K >> 6;           // K-tiles of 64
    const int HMAX = nkt << 2;         // total half-tiles

    const ushort_t* gA = A  + (size_t)row0 * K;
    const ushort_t* gB = Bw + (size_t)col0 * K;

    f32x4 acc[8][4] = {};

    // stage one 16KB half-tile h: tile tau=h>>2, slot j=h&3 in [B0,B1,A0,A1]
    auto stage_half = [&](int h) {
        const int tau = h >> 2, j = h & 3;
        const int sbase = ((tau & 1) << 15) | (j << 13);      // ushort units
        const ushort_t* src = (j < 2) ? gB + (size_t)(j << 7) * K
                                      : gA + (size_t)((j - 2) << 7) * K;
        const int k0 = tau << 6;
#pragma unroll
        for (int i = 0; i < 2; i++) {
            const int boff = w * 2048 + i * 1024 + lane * 16; // byte off in half-tile
            const int row  = boff >> 7;                       // 0..127
            const int c16  = (boff >> 4) & 7;                 // 16B column
            const ushort_t* s = src + (size_t)row * K + k0 + ((c16 ^ (row & 7)) << 3);
            async_copy16(s, &smem[sbase + w * 1024 + i * 512]);  // wave-uniform dest
        }
    };
    // swizzled ds_read of one bf16x8 MFMA fragment
    auto ldA = [&](int buf, int rf, int s) -> bf16x8 {
        const int row = (rf << 4) + m16;
        const int c16 = ((s << 2) + ko) ^ (row & 7);
        return *(const bf16x8*)&smem[(buf << 15) + ((2 + wm) << 13) + (row << 6) + (c16 << 3)];
    };
    auto ldB = [&](int buf, int cf, int s) -> bf16x8 {
        const int row = ((wn & 1) << 6) + (cf << 4) + m16;
        const int c16 = ((s << 2) + ko) ^ (row & 7);
        return *(const bf16x8*)&smem[(buf << 15) + (wnh << 13) + (row << 6) + (c16 << 3)];
    };

    // prologue: tile0 fully + tile1 B-halves; wait tile0 (2 halves = 4 loads in flight)
    for (int h = 0; h < 6; ++h) stage_half(h);
    asm volatile("s_waitcnt vmcnt(4)" ::: "memory");
    __builtin_amdgcn_s_barrier();

    int h = 6;
    for (int t = 0; t < nkt; ++t) {
        const int buf = t & 1;
        bf16x8 aF[4][2], bC0[2][2], bC1[2][2];

        // ---- q0: reads A-rh0(8) + B-ch0(4); MFMA acc[0..3][0..1]
#pragma unroll
        for (int r = 0; r < 4; r++) { aF[r][0] = ldA(buf, r, 0); aF[r][1] = ldA(buf, r, 1); }
#pragma unroll
        for (int c = 0; c < 2; c++) { bC0[c][0] = ldB(buf, c, 0); bC0[c][1] = ldB(buf, c, 1); }
        if (h < HMAX) stage_half(h);
        ++h;
        __builtin_amdgcn_s_barrier();
        __builtin_amdgcn_s_setprio(1);
#pragma unroll
        for (int r = 0; r < 4; r++)
#pragma unroll
            for (int c = 0; c < 2; c++) {
                acc[r][c] = mfma_bf16(aF[r][0], bC0[c][0], acc[r][c], 0, 0, 0);
                acc[r][c] = mfma_bf16(aF[r][1], bC0[c][1], acc[r][c], 0, 0, 0);
            }
        __builtin_amdgcn_s_setprio(0);
        __builtin_amdgcn_s_barrier();

        // ---- q1: reads B-ch1(4); MFMA acc[0..3][2..3]
#pragma unroll
        for (int c = 0; c < 2; c++) { bC1[c][0] = ldB(buf, 2 + c, 0); bC1[c][1] = ldB(buf, 2 + c, 1); }
        if (h < HMAX) stage_half(h);
        ++h;
        __builtin_amdgcn_s_barrier();
        __builtin_amdgcn_s_setprio(1);
#pragma unroll
        for (int r = 0; r < 4; r++)
#pragma unroll
            for (int c = 0; c < 2; c++) {
                acc[r][2 + c] = mfma_bf16(aF[r][0], bC1[c][0], acc[r][2 + c], 0, 0, 0);
                acc[r][2 + c] = mfma_bf16(aF[r][1], bC1[c][1], acc[r][2 + c], 0, 0, 0);
            }
        __builtin_amdgcn_s_setprio(0);
        __builtin_amdgcn_s_barrier();

        // ---- q2: reads A-rh1(8); MFMA acc[4..7][2..3]
#pragma unroll
        for (int r = 0; r < 4; r++) { aF[r][0] = ldA(buf, 4 + r, 0); aF[r][1] = ldA(buf, 4 + r, 1); }
        if (h < HMAX) stage_half(h);
        ++h;
        __builtin_amdgcn_s_barrier();
        __builtin_amdgcn_s_setprio(1);
#pragma unroll
        for (int r = 0; r < 4; r++)
#pragma unroll
            for (int c = 0; c < 2; c++) {
                acc[4 + r][2 + c] = mfma_bf16(aF[r][0], bC1[c][0], acc[4 + r][2 + c], 0, 0, 0);
                acc[4 + r][2 + c] = mfma_bf16(aF[r][1], bC1[c][1], acc[4 + r][2 + c], 0, 0, 0);
            }
        __builtin_amdgcn_s_setprio(0);
        __builtin_amdgcn_s_barrier();

        // ---- q3: no reads (bC0 held); MFMA acc[4..7][0..1]; tile-boundary vmcnt
        if (h < HMAX) stage_half(h);
        ++h;
        __builtin_amdgcn_s_barrier();
        __builtin_amdgcn_s_setprio(1);
#pragma unroll
        for (int r = 0; r < 4; r++)
#pragma unroll
            for (int c = 0; c < 2; c++) {
                acc[4 + r][c] = mfma_bf16(aF[r][0], bC0[c][0], acc[4 + r][c], 0, 0, 0);
                acc[4 + r][c] = mfma_bf16(aF[r][1], bC0[c][1], acc[4 + r][c], 0, 0, 0);
            }
        __builtin_amdgcn_s_setprio(0);
        if (t + 1 < nkt) {
            if (t + 1 == nkt - 1) asm volatile("s_waitcnt vmcnt(0)" ::: "memory");
            else                  asm volatile("s_waitcnt vmcnt(4)" ::: "memory");
            __builtin_amdgcn_s_barrier();
        }
    }

    // epilogue: C/D layout col = lane&15, row = (lane>>4)*4 + reg
    const int rbase = (lane >> 4) * 4;
#pragma unroll
    for (int i = 0; i < 8; i++) {
#pragma unroll
        for (int j = 0; j < 4; j++) {
#pragma unroll
            for (int r = 0; r < 4; r++) {
                int row = row0 + wm * 128 + i * 16 + rbase + r;
                int col = col0 + wn * 64 + j * 16 + m16;
                float v = acc[i][j][r] + bias[col];
                if (MODE == 0) {
                    if (col < INNER) {
                        oU0[(size_t)row * INNER + col] = f2bf(v);                // x_part bf16
                    } else {
                        float s = v / (1.f + __expf(-v));                        // silu(z)
                        oU1[(size_t)row * INNER + (col - INNER)] = f2bf(s);
                    }
                } else if (MODE == 1) {
                    if (col < INNER) {
                        float sp = fmaxf(v, 0.f) + log1pf(__expf(-fabsf(v)));    // softplus
                        oU0[(size_t)row * INNER + col] = f2bf(sp);               // dt bf16
                    } else if (col < INNER + 16) {
                        oB[(size_t)row * STATE + (col - INNER)] = v;             // Bm fp32
                    } else if (col < INNER + 32) {
                        oC[(size_t)row * STATE + (col - INNER - 16)] = v;        // Cm fp32
                    } // pad cols dropped
                } else {
                    oF[(size_t)row * N + col] = v;                               // d_out fp32
                }
            }
        }
    }
}

// ---------- causal depthwise conv (K=4) + silu; bf16 in, bf16 out ----------
// Vectorized x8 (G13): each thread owns 8 contiguous channels at one (b,l);
// u16x8 loads for the 4 tap rows, conv weights hoisted to registers.
__global__ void conv_silu_kernel(const ushort_t* __restrict__ xp, const float* __restrict__ cw,
                                 const float* __restrict__ cb,
                                 ushort_t* __restrict__ xcbf) {
    int i = blockIdx.x * 256 + threadIdx.x;     // over BL*INNER/8
    int base = i * 8;
    int d0 = base & (INNER - 1);
    int bl = base >> 11;
    int l  = bl & (LSEQ - 1);

    f32x4 wv[8];
    float acc[8];
#pragma unroll
    for (int j = 0; j < 8; j++) {
        wv[j]  = *(const f32x4*)&cw[(d0 + j) * KCONV];
        acc[j] = cb[d0 + j];
    }
#pragma unroll
    for (int k = 0; k < KCONV; k++) {
        int ls = l - (KCONV - 1) + k;
        if (ls >= 0) {
            u16x8 v = *(const u16x8*)&xp[base + (ls - l) * INNER];
#pragma unroll
            for (int j = 0; j < 8; j++) acc[j] = fmaf(wv[j][k], bf2f(v[j]), acc[j]);
        }
    }
    u16x8 o;
#pragma unroll
    for (int j = 0; j < 8; j++) {
        float s = acc[j] / (1.f + __expf(-acc[j]));
        o[j] = f2bf(s);
    }
    *(u16x8*)&xcbf[base] = o;
}

// ---------- chunked parallel scan, thread-per-channel ----------
__global__ __launch_bounds__(256) void scan_pass1(
    const ushort_t* __restrict__ dt, const ushort_t* __restrict__ xc,
    const float* __restrict__ Bm, const float* __restrict__ A_log,
    ushort_t* __restrict__ Pc, float* __restrict__ Sc)
{
    const int b = blockIdx.z;
    const int c = blockIdx.y;
    const int d = blockIdx.x * 256 + threadIdx.x;

    float A[STATE], h[STATE];
    {
        float al[STATE];
#pragma unroll
        for (int q = 0; q < 4; q++)
            *(f32x4*)(al + q * 4) = *(const f32x4*)(A_log + (size_t)d * STATE + q * 4);
#pragma unroll
        for (int s = 0; s < STATE; s++) { A[s] = -__expf(al[s]); h[s] = 0.f; }
    }
    float sdt = 0.f;
    const size_t base = (size_t)b * LSEQ + (size_t)c * TC;

#pragma unroll 2
    for (int t = 0; t < TC; t++) {
        const size_t r = base + t;
        const float dtv = bf2f(dt[r * INNER + d]);
        const float xv  = bf2f(xc[r * INNER + d]);
        const float dtx = dtv * xv;
        float Bv[STATE];
#pragma unroll
        for (int q = 0; q < 4; q++)
            *(f32x4*)(Bv + q * 4) = *(const f32x4*)(Bm + r * STATE + q * 4);
        sdt += dtv;
#pragma unroll
        for (int s = 0; s < STATE; s++) {
            const float dA = __expf(dtv * A[s]);
            h[s] = fmaf(dA, h[s], dtx * Bv[s]);
        }
    }

    const size_t idx = ((size_t)(b * NCH + c) * INNER + d) * STATE;
#pragma unroll
    for (int q = 0; q < 4; q++)
        *(f32x4*)(Sc + idx + q * 4) = *(const f32x4*)(h + q * 4);
    u16x8 p0, p1;
#pragma unroll
    for (int s = 0; s < 8; s++) { p0[s] = f2bf(__expf(A[s] * sdt)); }
#pragma unroll
    for (int s = 0; s < 8; s++) { p1[s] = f2bf(__expf(A[s + 8] * sdt)); }
    *(u16x8*)(Pc + idx)     = p0;
    *(u16x8*)(Pc + idx + 8) = p1;
}

// Pass 2: exclusive scan over chunks (in-place: S becomes H = chunk-initial state).
__global__ __launch_bounds__(256) void scan_pass2(
    const ushort_t* __restrict__ Pc, float* Sc)
{
    const int i = blockIdx.x * 256 + threadIdx.x;      // over BSZ*INNER*STATE
    const int b   = i >> 15;                           // / (INNER*STATE)
    const int rem = i & (INNER * STATE - 1);
    float H = 0.f;
#pragma unroll 8
    for (int c = 0; c < NCH; c++) {
        const size_t idx = (size_t)(b * NCH + c) * (INNER * STATE) + rem;
        const float Pv = bf2f(Pc[idx]);
        const float Sv = Sc[idx];
        const float Hn = fmaf(Pv, H, Sv);
        Sc[idx] = H;                                   // exclusive: h at chunk start
        H = Hn;
    }
}

// Pass 3: re-run local scan seeded with H; y = sum_s h[s]*C[s] + D*x; gate with
// silu(z) in-place. No shuffles: states are registers.
__global__ __launch_bounds__(256) void scan_pass3(
    const ushort_t* __restrict__ dt, const ushort_t* __restrict__ xc,
    const float* __restrict__ Bm, const float* __restrict__ Cm,
    const float* __restrict__ A_log, const float* __restrict__ Dv,
    const float* __restrict__ Hc, ushort_t* sz_y)
{
    const int b = blockIdx.z;
    const int c = blockIdx.y;
    const int d = blockIdx.x * 256 + threadIdx.x;

    float A[STATE], h[STATE];
    {
        float al[STATE];
#pragma unroll
        for (int q = 0; q < 4; q++)
            *(f32x4*)(al + q * 4) = *(const f32x4*)(A_log + (size_t)d * STATE + q * 4);
#pragma unroll
        for (int s = 0; s < STATE; s++) A[s] = -__expf(al[s]);
    }
    const size_t hidx = ((size_t)(b * NCH + c) * INNER + d) * STATE;
#pragma unroll
    for (int q = 0; q < 4; q++)
        *(f32x4*)(h + q * 4) = *(const f32x4*)(Hc + hidx + q * 4);

    const float Dd = Dv[d];
    const size_t base = (size_t)b * LSEQ + (size_t)c * TC;

#pragma unroll 2
    for (int t = 0; t < TC; t++) {
        const size_t r = base + t;
        const float dtv = bf2f(dt[r * INNER + d]);
        const float xv  = bf2f(xc[r * INNER + d]);
        const float dtx = dtv * xv;
        float Bv[STATE], Cv[STATE];
#pragma unroll
        for (int q = 0; q < 4; q++) {
            *(f32x4*)(Bv + q * 4) = *(const f32x4*)(Bm + r * STATE + q * 4);
            *(f32x4*)(Cv + q * 4) = *(const f32x4*)(Cm + r * STATE + q * 4);
        }
        float y = Dd * xv;
#pragma unroll
        for (int s = 0; s < STATE; s++) {
            const float dA = __expf(dtv * A[s]);
            h[s] = fmaf(dA, h[s], dtx * Bv[s]);
            y = fmaf(h[s], Cv[s], y);
        }
        const float zv = bf2f(sz_y[r * INNER + d]);
        sz_y[r * INNER + d] = f2bf(y * zv);
    }
}

// ---------- launch ----------
extern "C" void kernel_launch(void* const* d_in, const int* in_sizes, int n_in,
                              void* d_out, int out_size, void* d_ws, size_t ws_size,
                              hipStream_t stream) {
    const float* x       = (const float*)d_in[0];
    const float* in_w    = (const float*)d_in[1];
    const float* in_b    = (const float*)d_in[2];
    const float* conv_w  = (const float*)d_in[3];
    const float* conv_b  = (const float*)d_in[4];
    const float* dt_w    = (const float*)d_in[5];
    const float* dt_b    = (const float*)d_in[6];
    const float* A_log   = (const float*)d_in[7];
    const float* B_w     = (const float*)d_in[8];
    const float* B_b     = (const float*)d_in[9];
    const float* C_w     = (const float*)d_in[10];
    const float* C_b     = (const float*)d_in[11];
    const float* Dv      = (const float*)d_in[12];
    const float* out_w   = (const float*)d_in[13];
    const float* out_b   = (const float*)d_in[14];
    float* out = (float*)d_out;

    char* ws = (char*)d_ws;
    size_t off = 0;
    auto alloc = [&](size_t bytes) { size_t o = off; off += (bytes + 255) & ~(size_t)255; return o; };

    ushort_t* Xbf     = (ushort_t*)(ws + alloc((size_t)BL * HID * 2));       // 32 MB   [dead after GEMM1]
    ushort_t* W1bf    = (ushort_t*)(ws + alloc((size_t)2 * INNER * HID * 2));// 8 MB    [dead after GEMM1]
    ushort_t* Wcat    = (ushort_t*)(ws + alloc((size_t)NCAT * INNER * 2));   // 9.4 MB  [dead after GEMM2]
    ushort_t* Woutbf  = (ushort_t*)(ws + alloc((size_t)HID * INNER * 2));    // 4 MB
    float*    biascat = (float*)   (ws + alloc((size_t)NCAT * 4));
    ushort_t* xpart   = (ushort_t*)(ws + alloc((size_t)BL * INNER * 2));     // 64 MB, reused as dt
    ushort_t* szbf    = (ushort_t*)(ws + alloc((size_t)BL * INNER * 2));     // 64 MB, y in-place
    ushort_t* xconvbf = (ushort_t*)(ws + alloc((size_t)BL * INNER * 2));     // 64 MB
    float*    Bmbuf   = (float*)   (ws + alloc((size_t)BL * STATE * 4));     // 1 MB
    float*    Cmbuf   = (float*)   (ws + alloc((size_t)BL * STATE * 4));     // 1 MB
    ushort_t* dtbuf   = xpart;   // x_part dead after conv

    // Chunk-scan scratch overlays the dead Xbf/W1bf/Wcat region (~49.4 MB):
    //   P bf16: 16 MB at ws+0; S fp32: 32 MB after (48 MB total, fits)
    ushort_t* Pbuf = (ushort_t*)ws;
    float*    Sbuf = (float*)(ws + (size_t)NCH * BSZ * INNER * STATE * 2);
    (void)in_sizes; (void)n_in; (void)out_size;

    // If workspace is too small, skip launches: harness reports clean absmax
    // failure (== max|ref|) instead of a device page-fault core dump.
    if (ws_size < off) return;

    // casts / weight packing
    {
        int n = BL * HID;
        cast_bf16_kernel<<<(n + 255) / 256, 256, 0, stream>>>(x, Xbf, n);
        n = 2 * INNER * HID;
        cast_bf16_kernel<<<(n + 255) / 256, 256, 0, stream>>>(in_w, W1bf, n);
        n = HID * INNER;
        cast_bf16_kernel<<<(n + 255) / 256, 256, 0, stream>>>(out_w, Woutbf, n);
        n = NCAT * INNER;
        build_wcat_kernel<<<(n + 255) / 256, 256, 0, stream>>>(dt_w, B_w, C_w, Wcat);
        build_biascat_kernel<<<(NCAT + 255) / 256, 256, 0, stream>>>(dt_b, B_b, C_b, biascat);
    }

    // GEMM1: xz = x @ in_proj_w^T + b  -> x_part bf16, silu(z) bf16
    gemm256_kernel<0><<<dim3((2 * INNER) / 256, BL / 256), 512, 0, stream>>>(
        Xbf, W1bf, in_b, xpart, szbf, nullptr, nullptr, nullptr, 2 * INNER, HID);

    // causal depthwise conv + silu -> x_conv bf16
    conv_silu_kernel<<<(BL * INNER / 8) / 256, 256, 0, stream>>>(xpart, conv_w, conv_b, xconvbf);

    // GEMM2: [dt_pre | Bm | Cm | pad] = x_conv @ Wcat^T + biascat ; softplus fused for dt
    gemm256_kernel<1><<<dim3(NCAT / 256, BL / 256), 512, 0, stream>>>(
        xconvbf, Wcat, biascat, dtbuf, nullptr, nullptr, Bmbuf, Cmbuf, NCAT, INNER);

    // chunked selective scan (+ D*x, * silu(z)) -> y_gated bf16 (in-place over silu(z))
    scan_pass1<<<dim3(INNER / 256, NCH, BSZ), 256, 0, stream>>>(
        dtbuf, xconvbf, Bmbuf, A_log, Pbuf, Sbuf);
    scan_pass2<<<(BSZ * INNER * STATE) / 256, 256, 0, stream>>>(Pbuf, Sbuf);
    scan_pass3<<<dim3(INNER / 256, NCH, BSZ), 256, 0, stream>>>(
        dtbuf, xconvbf, Bmbuf, Cmbuf, A_log, Dv, Sbuf, szbf);

    // GEMM3: out = y_gated @ out_w^T + out_b
    gemm256_kernel<2><<<dim3(HID / 256, BL / 256), 512, 0, stream>>>(
        szbf, Woutbf, out_b, nullptr, nullptr, out, nullptr, nullptr, HID, INNER);
}

// Round 5
// 1032.284 us; speedup vs baseline: 1.2710x; 1.0556x over previous
//
#include <hip/hip_runtime.h>
#include <hip/hip_bf16.h>

// MambaSSMBlock: HID=1024, STATE=16, K=4, EXPAND=2, INNER=2048, B=4, L=4096
#define HID   1024
#define STATE 16
#define KCONV 4
#define INNER 2048
#define BSZ   4
#define LSEQ  4096
#define BL    (BSZ * LSEQ)       // 16384 rows
#define NCAT  2304               // 2048 (dt) + 16 (B) + 16 (C) + 224 pad -> 9 tiles of 256
#define NCH   64                 // scan chunks
#define TC    64                 // steps per chunk (NCH*TC == LSEQ)

typedef unsigned short ushort_t;
typedef unsigned int   uint_t;
typedef __attribute__((ext_vector_type(8))) __bf16 bf16x8;
typedef __attribute__((ext_vector_type(4))) float  f32x4;
typedef __attribute__((ext_vector_type(8))) unsigned short u16x8;

// ---------- helpers ----------
__device__ __forceinline__ ushort_t f2bf(float f) {
    uint_t u = __float_as_uint(f);
    u += 0x7fffu + ((u >> 16) & 1u);       // RNE (finite values only here)
    return (ushort_t)(u >> 16);
}
__device__ __forceinline__ float bf2f(ushort_t h) {
    return __uint_as_float(((uint_t)h) << 16);
}

#define AS1 __attribute__((address_space(1)))
#define AS3 __attribute__((address_space(3)))
__device__ __forceinline__ void async_copy16(const ushort_t* g, ushort_t* l) {
    // LDS dest is wave-uniform base; HW writes lane i at base + i*16B
    __builtin_amdgcn_global_load_lds((const AS1 void*)g, (AS3 void*)l, 16, 0, 0);
}

// ---------- elementwise cast ----------
__global__ void cast_bf16_kernel(const float* __restrict__ src, ushort_t* __restrict__ dst, int n) {
    int i = blockIdx.x * 256 + threadIdx.x;
    if (i < n) dst[i] = f2bf(src[i]);
}

// ---------- build concatenated [dt_w; B_w; C_w; 0-pad] bf16 weight (NCAT x 2048) ----------
__global__ void build_wcat_kernel(const float* __restrict__ dtw, const float* __restrict__ Bw,
                                  const float* __restrict__ Cw, ushort_t* __restrict__ out) {
    int i = blockIdx.x * 256 + threadIdx.x;
    if (i >= NCAT * INNER) return;
    int r = i >> 11;           // / 2048
    int k = i & (INNER - 1);
    float v = 0.f;
    if (r < INNER)            v = dtw[i];
    else if (r < INNER + 16)  v = Bw[(r - INNER) * INNER + k];
    else if (r < INNER + 32)  v = Cw[(r - INNER - 16) * INNER + k];
    out[i] = f2bf(v);
}

__global__ void build_biascat_kernel(const float* __restrict__ dtb, const float* __restrict__ Bb,
                                     const float* __restrict__ Cb, float* __restrict__ out) {
    int i = blockIdx.x * 256 + threadIdx.x;
    if (i >= NCAT) return;
    float v = 0.f;
    if (i < INNER)            v = dtb[i];
    else if (i < INNER + 16)  v = Bb[i - INNER];
    else if (i < INNER + 32)  v = Cb[i - INNER - 16];
    out[i] = v;
}

// ---------- 256x256x64 8-phase bf16 MFMA GEMM: C = A(M,K) @ B(N,K)^T ----------
// 8 waves (2Mx4N), 512 threads, 128KiB LDS = 2 K-tile bufs x [B0|B1|A0|A1] x 16KB.
// Per K-tile: 4 phases, each = {ds_reads || stage 1 half-tile -> s_barrier ->
// setprio(1) 16 MFMA setprio(0) -> s_barrier}; counted vmcnt(4) once per K-tile,
// vmcnt(0) only before the last tile (T3+T4). LDS XOR-swizzle (T2, conflict-free,
// verified 0 SQ_LDS_BANK_CONFLICT in R3).
// R4/R5 changes vs R3 (same schedule; R3 passed correctness):
//  - K templated (KK); per-lane base ptrs pA/pB precomputed; stage addr =
//    pX + const(j,i)*KK + tau*64 -> 2 VALU adds/stage instead of per-call
//    64-bit row*K muls. Removes the register-pressure spike that spilled
//    (R3: WRITE_SIZE 367MB vs 128MB ideal = spill round-trip signature).
//  - Epilogue via per-wave-private LDS transpose -> u16x8 full-line stores
//    (was 2B scalar scatter). MODE2 keeps direct fp32 (already full-line).
// Race note: bC0/bC1 are register-held; every ds_read is force-completed by
// its consuming MFMA's lgkmcnt within the same phase, and same-slot DMA
// overwrites are issued >=1 full phase after that -> no LDS W-after-R race.
#define mfma_bf16 __builtin_amdgcn_mfma_f32_16x16x32_bf16

template <int MODE, int KK>
__global__ __launch_bounds__(512, 2) void gemm256_kernel(
    const ushort_t* __restrict__ A, const ushort_t* __restrict__ Bw,
    const float* __restrict__ bias,
    ushort_t* __restrict__ oU0, ushort_t* __restrict__ oU1,
    float* __restrict__ oF, float* __restrict__ oB, float* __restrict__ oC,
    int N)
{
    __shared__ ushort_t smem[65536];   // 128 KiB

    const int tid  = threadIdx.x;
    const int w    = tid >> 6;
    const int lane = tid & 63;
    const int m16  = lane & 15;
    const int ko   = lane >> 4;        // 0..3 : which 8-elem k-chunk
    const int wm   = w >> 2;           // 0..1 : row-half of the 256-row tile
    const int wn   = w & 3;            // 0..3 : 64-col quarter
    const int wnh  = wn >> 1;          // B half-tile index

    // ----- XCD-banded swizzle (gridDim.y == 64, nwg % 8 == 0 for all shapes) -----
    const int gx   = gridDim.x;
    const int lb   = blockIdx.y * gx + blockIdx.x;
    const int xcd  = lb & 7;
    const int slot = lb >> 3;
    const int tx   = slot % gx;
    const int ty   = xcd * 8 + slot / gx;    // 8 row-tiles per XCD band
    const int row0 = ty * 256;
    const int col0 = tx * 256;

    constexpr int NKT = KK >> 6;       // K-tiles of 64

    // per-lane staging bases (swizzle pre-applied to the GLOBAL source; LDS
    // dest stays linear -- rule #21): lane covers row (w*16 + lane/8 [+i*8]),
    // 16B chunk c16 = lane&7, src chunk = c16 ^ (row&7) = (lane&7)^(lane>>3).
    const size_t Lofs = (size_t)(w * 16 + (lane >> 3)) * KK
                      + (size_t)(((lane & 7) ^ (lane >> 3)) << 3);
    const ushort_t* pA = A  + (size_t)row0 * KK + Lofs;
    const ushort_t* pB = Bw + (size_t)col0 * KK + Lofs;

    f32x4 acc[8][4] = {};

    // stage one half-tile slot j (0,1 = B-halves; 2,3 = A-halves) of K-tile tau
    auto stage_half = [&](int j, int tau) {
        const int sb = ((tau & 1) << 15) | (j << 13);      // ushort units
        const ushort_t* px = (j < 2) ? pB : pA;
#pragma unroll
        for (int i = 0; i < 2; i++) {
            const ushort_t* s = px + (size_t)((j & 1) * 128 + i * 8) * KK + (tau << 6);
            async_copy16(s, &smem[sb + w * 1024 + i * 512]);
        }
    };
    // swizzled ds_read of one bf16x8 MFMA fragment
    auto ldA = [&](int buf, int rf, int s) -> bf16x8 {
        const int row = (rf << 4) + m16;
        const int c16 = ((s << 2) + ko) ^ (row & 7);
        return *(const bf16x8*)&smem[(buf << 15) + ((2 + wm) << 13) + (row << 6) + (c16 << 3)];
    };
    auto ldB = [&](int buf, int cf, int s) -> bf16x8 {
        const int row = ((wn & 1) << 6) + (cf << 4) + m16;
        const int c16 = ((s << 2) + ko) ^ (row & 7);
        return *(const bf16x8*)&smem[(buf << 15) + (wnh << 13) + (row << 6) + (c16 << 3)];
    };

    // prologue: tile0 fully + tile1 B-halves; wait tile0 (tile1's 4 loads stay in flight)
    stage_half(0, 0); stage_half(1, 0); stage_half(2, 0); stage_half(3, 0);
    stage_half(0, 1); stage_half(1, 1);
    asm volatile("s_waitcnt vmcnt(4)" ::: "memory");
    __builtin_amdgcn_s_barrier();

#pragma unroll 1
    for (int t = 0; t < NKT; ++t) {
        const int buf = t & 1;
        bf16x8 aF[4][2], bC0[2][2], bC1[2][2];

        // ---- q0: reads A-rh0(8) + B-ch0(4); stage A0(t+1); MFMA acc[0..3][0..1]
#pragma unroll
        for (int r = 0; r < 4; r++) { aF[r][0] = ldA(buf, r, 0); aF[r][1] = ldA(buf, r, 1); }
#pragma unroll
        for (int c = 0; c < 2; c++) { bC0[c][0] = ldB(buf, c, 0); bC0[c][1] = ldB(buf, c, 1); }
        if (t + 1 < NKT) stage_half(2, t + 1);
        __builtin_amdgcn_s_barrier();
        __builtin_amdgcn_s_setprio(1);
#pragma unroll
        for (int r = 0; r < 4; r++)
#pragma unroll
            for (int c = 0; c < 2; c++) {
                acc[r][c] = mfma_bf16(aF[r][0], bC0[c][0], acc[r][c], 0, 0, 0);
                acc[r][c] = mfma_bf16(aF[r][1], bC0[c][1], acc[r][c], 0, 0, 0);
            }
        __builtin_amdgcn_s_setprio(0);
        __builtin_amdgcn_s_barrier();

        // ---- q1: reads B-ch1(4); stage A1(t+1); MFMA acc[0..3][2..3]
#pragma unroll
        for (int c = 0; c < 2; c++) { bC1[c][0] = ldB(buf, 2 + c, 0); bC1[c][1] = ldB(buf, 2 + c, 1); }
        if (t + 1 < NKT) stage_half(3, t + 1);
        __builtin_amdgcn_s_barrier();
        __builtin_amdgcn_s_setprio(1);
#pragma unroll
        for (int r = 0; r < 4; r++)
#pragma unroll
            for (int c = 0; c < 2; c++) {
                acc[r][2 + c] = mfma_bf16(aF[r][0], bC1[c][0], acc[r][2 + c], 0, 0, 0);
                acc[r][2 + c] = mfma_bf16(aF[r][1], bC1[c][1], acc[r][2 + c], 0, 0, 0);
            }
        __builtin_amdgcn_s_setprio(0);
        __builtin_amdgcn_s_barrier();

        // ---- q2: reads A-rh1(8); stage B0(t+2); MFMA acc[4..7][2..3]
#pragma unroll
        for (int r = 0; r < 4; r++) { aF[r][0] = ldA(buf, 4 + r, 0); aF[r][1] = ldA(buf, 4 + r, 1); }
        if (t + 2 < NKT) stage_half(0, t + 2);
        __builtin_amdgcn_s_barrier();
        __builtin_amdgcn_s_setprio(1);
#pragma unroll
        for (int r = 0; r < 4; r++)
#pragma unroll
            for (int c = 0; c < 2; c++) {
                acc[4 + r][2 + c] = mfma_bf16(aF[r][0], bC1[c][0], acc[4 + r][2 + c], 0, 0, 0);
                acc[4 + r][2 + c] = mfma_bf16(aF[r][1], bC1[c][1], acc[4 + r][2 + c], 0, 0, 0);
            }
        __builtin_amdgcn_s_setprio(0);
        __builtin_amdgcn_s_barrier();

        // ---- q3: no reads (bC0 held); stage B1(t+2); MFMA acc[4..7][0..1]
        if (t + 2 < NKT) stage_half(1, t + 2);
        __builtin_amdgcn_s_barrier();
        __builtin_amdgcn_s_setprio(1);
#pragma unroll
        for (int r = 0; r < 4; r++)
#pragma unroll
            for (int c = 0; c < 2; c++) {
                acc[4 + r][c] = mfma_bf16(aF[r][0], bC0[c][0], acc[4 + r][c], 0, 0, 0);
                acc[4 + r][c] = mfma_bf16(aF[r][1], bC0[c][1], acc[4 + r][c], 0, 0, 0);
            }
        __builtin_amdgcn_s_setprio(0);
        if (t + 1 < NKT) {
            if (t + 1 == NKT - 1) asm volatile("s_waitcnt vmcnt(0)" ::: "memory");
            else                  asm volatile("s_waitcnt vmcnt(4)" ::: "memory");
            __builtin_amdgcn_s_barrier();
        }
    }

    // ---------------- epilogue ----------------
    // C/D layout: col = lane&15, row = (lane>>4)*4 + reg
    const int rbase = (lane >> 4) * 4;
    __syncthreads();   // all K-loop LDS reads done before smem reuse; drains cnts

    if (MODE == 2) {
        // fp32 direct: 16 lanes x 4B contiguous = full 64B line per store instr
#pragma unroll
        for (int i = 0; i < 8; i++)
#pragma unroll
            for (int j = 0; j < 4; j++)
#pragma unroll
                for (int r = 0; r < 4; r++) {
                    int row = row0 + wm * 128 + i * 16 + rbase + r;
                    int col = col0 + wn * 64 + j * 16 + m16;
                    oF[(size_t)row * N + col] = acc[i][j][r] + bias[col];
                }
    } else if (MODE == 1 && col0 >= INNER) {
        // Bm/Cm strip (cols 2048..2079) + pad: scalar fp32, tiny
#pragma unroll
        for (int i = 0; i < 8; i++)
#pragma unroll
            for (int j = 0; j < 4; j++)
#pragma unroll
                for (int r = 0; r < 4; r++) {
                    int row = row0 + wm * 128 + i * 16 + rbase + r;
                    int col = col0 + wn * 64 + j * 16 + m16;
                    float v = acc[i][j][r] + bias[col];
                    if (col < INNER + 16)      oB[(size_t)row * STATE + (col - INNER)] = v;
                    else if (col < INNER + 32) oC[(size_t)row * STATE + (col - INNER - 16)] = v;
                }
    } else {
        // bf16 modes: per-wave-private LDS transpose -> u16x8 full-line stores
        const bool isZ = (MODE == 0) && (col0 >= INNER);   // block-uniform
        ushort_t* my = &smem[w * 8192];                    // 16KB/wave region
        const int SW = 68;                                 // padded row stride
#pragma unroll
        for (int p = 0; p < 2; p++) {                      // row-halves of 128
#pragma unroll
            for (int i4 = 0; i4 < 4; i4++)
#pragma unroll
                for (int j = 0; j < 4; j++)
#pragma unroll
                    for (int r = 0; r < 4; r++) {
                        int lr = i4 * 16 + rbase + r;      // 0..63
                        int lc = j * 16 + m16;             // 0..63
                        float v = acc[p * 4 + i4][j][r] + bias[col0 + wn * 64 + lc];
                        ushort_t o;
                        if (MODE == 0) {
                            if (isZ) { float s = v / (1.f + __expf(-v)); o = f2bf(s); }
                            else     { o = f2bf(v); }
                        } else {
                            float sp = fmaxf(v, 0.f) + log1pf(__expf(-fabsf(v)));
                            o = f2bf(sp);
                        }
                        my[lr * SW + lc] = o;
                    }
            // same-wave DS ordering (HW in-order per wave); sched_barrier as
            // insurance against any compile-time reordering of the read loop
            __builtin_amdgcn_sched_barrier(0);
#pragma unroll
            for (int it = 0; it < 8; it++) {
                int lr = it * 8 + (lane >> 3);
                u16x8 vv = *(const u16x8*)&my[lr * SW + (lane & 7) * 8];
                int grow = row0 + wm * 128 + p * 64 + lr;
                int gcol = col0 + wn * 64 + (lane & 7) * 8;
                if (MODE == 0 && isZ)
                    *(u16x8*)&oU1[(size_t)grow * INNER + (gcol - INNER)] = vv;
                else
                    *(u16x8*)&oU0[(size_t)grow * INNER + gcol] = vv;
            }
            __builtin_amdgcn_sched_barrier(0);
        }
    }
}

// ---------- causal depthwise conv (K=4) + silu; bf16 in, bf16 out ----------
// Vectorized x8 (G13): each thread owns 8 contiguous channels at one (b,l);
// u16x8 loads for the 4 tap rows, conv weights hoisted to registers.
__global__ void conv_silu_kernel(const ushort_t* __restrict__ xp, const float* __restrict__ cw,
                                 const float* __restrict__ cb,
                                 ushort_t* __restrict__ xcbf) {
    int i = blockIdx.x * 256 + threadIdx.x;     // over BL*INNER/8
    int base = i * 8;
    int d0 = base & (INNER - 1);
    int bl = base >> 11;
    int l  = bl & (LSEQ - 1);

    f32x4 wv[8];
    float acc[8];
#pragma unroll
    for (int j = 0; j < 8; j++) {
        wv[j]  = *(const f32x4*)&cw[(d0 + j) * KCONV];
        acc[j] = cb[d0 + j];
    }
#pragma unroll
    for (int k = 0; k < KCONV; k++) {
        int ls = l - (KCONV - 1) + k;
        if (ls >= 0) {
            u16x8 v = *(const u16x8*)&xp[base + (ls - l) * INNER];
#pragma unroll
            for (int j = 0; j < 8; j++) acc[j] = fmaf(wv[j][k], bf2f(v[j]), acc[j]);
        }
    }
    u16x8 o;
#pragma unroll
    for (int j = 0; j < 8; j++) {
        float s = acc[j] / (1.f + __expf(-acc[j]));
        o[j] = f2bf(s);
    }
    *(u16x8*)&xcbf[base] = o;
}

// ---------- chunked parallel scan, thread-per-channel ----------
__global__ __launch_bounds__(256) void scan_pass1(
    const ushort_t* __restrict__ dt, const ushort_t* __restrict__ xc,
    const float* __restrict__ Bm, const float* __restrict__ A_log,
    ushort_t* __restrict__ Pc, float* __restrict__ Sc)
{
    const int b = blockIdx.z;
    const int c = blockIdx.y;
    const int d = blockIdx.x * 256 + threadIdx.x;

    float A[STATE], h[STATE];
    {
        float al[STATE];
#pragma unroll
        for (int q = 0; q < 4; q++)
            *(f32x4*)(al + q * 4) = *(const f32x4*)(A_log + (size_t)d * STATE + q * 4);
#pragma unroll
        for (int s = 0; s < STATE; s++) { A[s] = -__expf(al[s]); h[s] = 0.f; }
    }
    float sdt = 0.f;
    const size_t base = (size_t)b * LSEQ + (size_t)c * TC;

#pragma unroll 2
    for (int t = 0; t < TC; t++) {
        const size_t r = base + t;
        const float dtv = bf2f(dt[r * INNER + d]);
        const float xv  = bf2f(xc[r * INNER + d]);
        const float dtx = dtv * xv;
        float Bv[STATE];
#pragma unroll
        for (int q = 0; q < 4; q++)
            *(f32x4*)(Bv + q * 4) = *(const f32x4*)(Bm + r * STATE + q * 4);
        sdt += dtv;
#pragma unroll
        for (int s = 0; s < STATE; s++) {
            const float dA = __expf(dtv * A[s]);
            h[s] = fmaf(dA, h[s], dtx * Bv[s]);
        }
    }

    const size_t idx = ((size_t)(b * NCH + c) * INNER + d) * STATE;
#pragma unroll
    for (int q = 0; q < 4; q++)
        *(f32x4*)(Sc + idx + q * 4) = *(const f32x4*)(h + q * 4);
    u16x8 p0, p1;
#pragma unroll
    for (int s = 0; s < 8; s++) { p0[s] = f2bf(__expf(A[s] * sdt)); }
#pragma unroll
    for (int s = 0; s < 8; s++) { p1[s] = f2bf(__expf(A[s + 8] * sdt)); }
    *(u16x8*)(Pc + idx)     = p0;
    *(u16x8*)(Pc + idx + 8) = p1;
}

// Pass 2: exclusive scan over chunks (in-place: S becomes H = chunk-initial state).
__global__ __launch_bounds__(256) void scan_pass2(
    const ushort_t* __restrict__ Pc, float* Sc)
{
    const int i = blockIdx.x * 256 + threadIdx.x;      // over BSZ*INNER*STATE
    const int b   = i >> 15;                           // / (INNER*STATE)
    const int rem = i & (INNER * STATE - 1);
    float H = 0.f;
#pragma unroll 8
    for (int c = 0; c < NCH; c++) {
        const size_t idx = (size_t)(b * NCH + c) * (INNER * STATE) + rem;
        const float Pv = bf2f(Pc[idx]);
        const float Sv = Sc[idx];
        const float Hn = fmaf(Pv, H, Sv);
        Sc[idx] = H;                                   // exclusive: h at chunk start
        H = Hn;
    }
}

// Pass 3: re-run local scan seeded with H; y = sum_s h[s]*C[s] + D*x; gate with
// silu(z) in-place. No shuffles: states are registers.
__global__ __launch_bounds__(256) void scan_pass3(
    const ushort_t* __restrict__ dt, const ushort_t* __restrict__ xc,
    const float* __restrict__ Bm, const float* __restrict__ Cm,
    const float* __restrict__ A_log, const float* __restrict__ Dv,
    const float* __restrict__ Hc, ushort_t* sz_y)
{
    const int b = blockIdx.z;
    const int c = blockIdx.y;
    const int d = blockIdx.x * 256 + threadIdx.x;

    float A[STATE], h[STATE];
    {
        float al[STATE];
#pragma unroll
        for (int q = 0; q < 4; q++)
            *(f32x4*)(al + q * 4) = *(const f32x4*)(A_log + (size_t)d * STATE + q * 4);
#pragma unroll
        for (int s = 0; s < STATE; s++) A[s] = -__expf(al[s]);
    }
    const size_t hidx = ((size_t)(b * NCH + c) * INNER + d) * STATE;
#pragma unroll
    for (int q = 0; q < 4; q++)
        *(f32x4*)(h + q * 4) = *(const f32x4*)(Hc + hidx + q * 4);

    const float Dd = Dv[d];
    const size_t base = (size_t)b * LSEQ + (size_t)c * TC;

#pragma unroll 2
    for (int t = 0; t < TC; t++) {
        const size_t r = base + t;
        const float dtv = bf2f(dt[r * INNER + d]);
        const float xv  = bf2f(xc[r * INNER + d]);
        const float dtx = dtv * xv;
        float Bv[STATE], Cv[STATE];
#pragma unroll
        for (int q = 0; q < 4; q++) {
            *(f32x4*)(Bv + q * 4) = *(const f32x4*)(Bm + r * STATE + q * 4);
            *(f32x4*)(Cv + q * 4) = *(const f32x4*)(Cm + r * STATE + q * 4);
        }
        float y = Dd * xv;
#pragma unroll
        for (int s = 0; s < STATE; s++) {
            const float dA = __expf(dtv * A[s]);
            h[s] = fmaf(dA, h[s], dtx * Bv[s]);
            y = fmaf(h[s], Cv[s], y);
        }
        const float zv = bf2f(sz_y[r * INNER + d]);
        sz_y[r * INNER + d] = f2bf(y * zv);
    }
}

// ---------- launch ----------
extern "C" void kernel_launch(void* const* d_in, const int* in_sizes, int n_in,
                              void* d_out, int out_size, void* d_ws, size_t ws_size,
                              hipStream_t stream) {
    const float* x       = (const float*)d_in[0];
    const float* in_w    = (const float*)d_in[1];
    const float* in_b    = (const float*)d_in[2];
    const float* conv_w  = (const float*)d_in[3];
    const float* conv_b  = (const float*)d_in[4];
    const float* dt_w    = (const float*)d_in[5];
    const float* dt_b    = (const float*)d_in[6];
    const float* A_log   = (const float*)d_in[7];
    const float* B_w     = (const float*)d_in[8];
    const float* B_b     = (const float*)d_in[9];
    const float* C_w     = (const float*)d_in[10];
    const float* C_b     = (const float*)d_in[11];
    const float* Dv      = (const float*)d_in[12];
    const float* out_w   = (const float*)d_in[13];
    const float* out_b   = (const float*)d_in[14];
    float* out = (float*)d_out;

    char* ws = (char*)d_ws;
    size_t off = 0;
    auto alloc = [&](size_t bytes) { size_t o = off; off += (bytes + 255) & ~(size_t)255; return o; };

    ushort_t* Xbf     = (ushort_t*)(ws + alloc((size_t)BL * HID * 2));       // 32 MB   [dead after GEMM1]
    ushort_t* W1bf    = (ushort_t*)(ws + alloc((size_t)2 * INNER * HID * 2));// 8 MB    [dead after GEMM1]
    ushort_t* Wcat    = (ushort_t*)(ws + alloc((size_t)NCAT * INNER * 2));   // 9.4 MB  [dead after GEMM2]
    ushort_t* Woutbf  = (ushort_t*)(ws + alloc((size_t)HID * INNER * 2));    // 4 MB
    float*    biascat = (float*)   (ws + alloc((size_t)NCAT * 4));
    ushort_t* xpart   = (ushort_t*)(ws + alloc((size_t)BL * INNER * 2));     // 64 MB, reused as dt
    ushort_t* szbf    = (ushort_t*)(ws + alloc((size_t)BL * INNER * 2));     // 64 MB, y in-place
    ushort_t* xconvbf = (ushort_t*)(ws + alloc((size_t)BL * INNER * 2));     // 64 MB
    float*    Bmbuf   = (float*)   (ws + alloc((size_t)BL * STATE * 4));     // 1 MB
    float*    Cmbuf   = (float*)   (ws + alloc((size_t)BL * STATE * 4));     // 1 MB
    ushort_t* dtbuf   = xpart;   // x_part dead after conv

    // Chunk-scan scratch overlays the dead Xbf/W1bf/Wcat region (~49.4 MB):
    //   P bf16: 16 MB at ws+0; S fp32: 32 MB after (48 MB total, fits)
    ushort_t* Pbuf = (ushort_t*)ws;
    float*    Sbuf = (float*)(ws + (size_t)NCH * BSZ * INNER * STATE * 2);
    (void)in_sizes; (void)n_in; (void)out_size;

    // If workspace is too small, skip launches: harness reports clean absmax
    // failure (== max|ref|) instead of a device page-fault core dump.
    if (ws_size < off) return;

    // casts / weight packing
    {
        int n = BL * HID;
        cast_bf16_kernel<<<(n + 255) / 256, 256, 0, stream>>>(x, Xbf, n);
        n = 2 * INNER * HID;
        cast_bf16_kernel<<<(n + 255) / 256, 256, 0, stream>>>(in_w, W1bf, n);
        n = HID * INNER;
        cast_bf16_kernel<<<(n + 255) / 256, 256, 0, stream>>>(out_w, Woutbf, n);
        n = NCAT * INNER;
        build_wcat_kernel<<<(n + 255) / 256, 256, 0, stream>>>(dt_w, B_w, C_w, Wcat);
        build_biascat_kernel<<<(NCAT + 255) / 256, 256, 0, stream>>>(dt_b, B_b, C_b, biascat);
    }

    // GEMM1: xz = x @ in_proj_w^T + b  -> x_part bf16, silu(z) bf16
    gemm256_kernel<0, HID><<<dim3((2 * INNER) / 256, BL / 256), 512, 0, stream>>>(
        Xbf, W1bf, in_b, xpart, szbf, nullptr, nullptr, nullptr, 2 * INNER);

    // causal depthwise conv + silu -> x_conv bf16
    conv_silu_kernel<<<(BL * INNER / 8) / 256, 256, 0, stream>>>(xpart, conv_w, conv_b, xconvbf);

    // GEMM2: [dt_pre | Bm | Cm | pad] = x_conv @ Wcat^T + biascat ; softplus fused for dt
    gemm256_kernel<1, INNER><<<dim3(NCAT / 256, BL / 256), 512, 0, stream>>>(
        xconvbf, Wcat, biascat, dtbuf, nullptr, nullptr, Bmbuf, Cmbuf, NCAT);

    // chunked selective scan (+ D*x, * silu(z)) -> y_gated bf16 (in-place over silu(z))
    scan_pass1<<<dim3(INNER / 256, NCH, BSZ), 256, 0, stream>>>(
        dtbuf, xconvbf, Bmbuf, A_log, Pbuf, Sbuf);
    scan_pass2<<<(BSZ * INNER * STATE) / 256, 256, 0, stream>>>(Pbuf, Sbuf);
    scan_pass3<<<dim3(INNER / 256, NCH, BSZ), 256, 0, stream>>>(
        dtbuf, xconvbf, Bmbuf, Cmbuf, A_log, Dv, Sbuf, szbf);

    // GEMM3: out = y_gated @ out_w^T + out_b
    gemm256_kernel<2, INNER><<<dim3(HID / 256, BL / 256), 512, 0, stream>>>(
        szbf, Woutbf, out_b, nullptr, nullptr, out, nullptr, nullptr, HID);
}